// Round 1
// baseline (2244.907 us; speedup 1.0000x reference)
//
#include <hip/hip_runtime.h>
#include <math.h>

#define DIM 128
#define HID 256
#define MT 64           // rows per block-tile
#define NT 512          // threads per block (8 waves)
#define H_STRIDE 136    // bf16 elems (68 dw ≡ 4 mod 32)
#define G_STRIDE 264    // bf16 elems (132 dw ≡ 4 mod 32), k-permuted packed layout
#define D_STRIDE 132    // f32 elems (132 dw ≡ 4 mod 32; write pattern is 2-way = free)

typedef __attribute__((ext_vector_type(8))) short bf16x8;
typedef __attribute__((ext_vector_type(4))) float f32x4;
typedef __attribute__((ext_vector_type(4))) unsigned int u32x4;

#define MFMA(a, b, c) __builtin_amdgcn_mfma_f32_16x16x32_bf16((a), (b), (c), 0, 0, 0)

__device__ __forceinline__ unsigned int pack2(float lo, float hi) {
    unsigned int a = __float_as_uint(lo) + 0x8000u;
    unsigned int b = __float_as_uint(hi) + 0x8000u;
    return __builtin_amdgcn_perm(b, a, 0x07060302u);  // [b.hi16 | a.hi16]
}
__device__ __forceinline__ unsigned short rb16(float f) {
    return (unsigned short)((__float_as_uint(f) + 0x8000u) >> 16);
}
__device__ __forceinline__ float frcp(float x) { return __builtin_amdgcn_rcpf(x); }
__device__ __forceinline__ float ex2(float x)  { return __builtin_amdgcn_exp2f(x); }
// tanh-form GELU, exp folded to exp2: g = t * 1/(1+2^(t*(A + B t^2)))
__device__ __forceinline__ float gelu_f(float t) {
    const float u = t * fmaf(t * t, -0.1029436f, -2.3022082f);
    return t * frcp(1.f + ex2(u));
}
__device__ __forceinline__ float sigm(float x) { return frcp(1.f + ex2(-1.442695f * x)); }
__device__ __forceinline__ f32x4 splat4(float v) { f32x4 r = {v, v, v, v}; return r; }

// ---- setup: w2g = w2 @ wg_r (256x128 @ 128x128) -> ws fp32; row 256 = bg + b2 @ wg_r ----
__global__ void w2g_setup(const float* __restrict__ w2, const float* __restrict__ wg,
                          const float* __restrict__ b2, const float* __restrict__ bg,
                          float* __restrict__ w2g)
{
    __shared__ float wr[DIM][DIM + 1];
    const int t = threadIdx.x;  // 256
    for (int i = t; i < DIM * DIM; i += 256)
        wr[i >> 7][i & 127] = wg[DIM * DIM + i];  // wg_r = wg[128:,:]
    __syncthreads();
    const int row = blockIdx.x * 32 + (t >> 3);  // 8 blocks x 32 rows
    const int c0  = (t & 7) * 16;
    float acc[16];
#pragma unroll
    for (int j = 0; j < 16; ++j) acc[j] = 0.f;
    for (int k = 0; k < DIM; ++k) {
        const float a = w2[row * DIM + k];
#pragma unroll
        for (int j = 0; j < 16; ++j) acc[j] = fmaf(a, wr[k][c0 + j], acc[j]);
    }
#pragma unroll
    for (int j = 0; j < 16; ++j) w2g[row * DIM + c0 + j] = acc[j];
    if (blockIdx.x == 0 && t < DIM) {
        float s = bg[t];
        for (int k = 0; k < DIM; ++k) s = fmaf(b2[k], wr[k][t], s);
        w2g[256 * DIM + t] = s;
    }
}

__global__ __launch_bounds__(NT, 4) void trw_kernel(
    const float* __restrict__ x,
    const float* __restrict__ ln_w, const float* __restrict__ ln_b,
    const float* __restrict__ w1, const float* __restrict__ b1,
    const float* __restrict__ w2, const float* __restrict__ b2,
    const float* __restrict__ wg,
    const float* __restrict__ w2g,
    const int* __restrict__ passes_p,
    float* __restrict__ out, int nrows)
{
    // gBuf (bf16 g, stage1-epi -> stage2 reads) and dBuf (f32 delta, stage2-epi -> next hub)
    // have disjoint lifetimes (a barrier separates the last gBuf read from the first dBuf
    // write) and identical footprints (G_STRIDE/2 == D_STRIDE == 132 dw), so they overlay.
    // LDS: 17408 + 33792 + 256 + 256 = 51712 B -> 2 blocks/CU (vs 85504 B = 1 block/CU).
    __shared__ __align__(16) unsigned short hBuf[MT * H_STRIDE];  // 17408 B
    __shared__ __align__(16) unsigned int gdBuf[MT * D_STRIDE];   // 33792 B overlay
    __shared__ __align__(16) float muB[MT];
    __shared__ __align__(16) float sgB[MT];
    unsigned short* gBuf = (unsigned short*)gdBuf;
    unsigned int* gBuf32 = gdBuf;
    float* dBuf = (float*)gdBuf;

    const int tid = threadIdx.x;
    const int w = tid >> 6, l = tid & 63, q = l >> 4, c16 = l & 15;
    const int hrow = tid >> 3;          // hub: 64 rows, 8 threads/row
    const int hcg  = (tid & 7) << 4;    // hub: 16 cols/thread
    const int np = passes_p[0];

    // ---- stage-1 B-frags: w1' = lw∘w1 coltiles {2w,2w+1}; wg_s coltile {w} ----
    const int colA = 32 * w + c16, colB = colA + 16, colG = 16 * w + c16;
    bf16x8 w1f[2][4], wgsf[4];
#pragma unroll
    for (int kk = 0; kk < 4; ++kk) {
        bf16x8 fa, fb, fg;
#pragma unroll
        for (int j = 0; j < 8; ++j) {
            const int k = kk * 32 + q * 8 + j;
            const float lwk = ln_w[k];
            fa[j] = (short)rb16(lwk * w1[k * HID + colA]);
            fb[j] = (short)rb16(lwk * w1[k * HID + colB]);
            fg[j] = (short)rb16(wg[k * DIM + colG]);
        }
        w1f[0][kk] = fa; w1f[1][kk] = fb; wgsf[kk] = fg;
    }
    // ---- stage-2 B-frags (k-permuted to match gBuf packing): w2 and w2g, coltile {w} ----
    bf16x8 w2f[8], w2gf[8];
#pragma unroll
    for (int kk = 0; kk < 8; ++kk) {
        bf16x8 f2, fg;
#pragma unroll
        for (int j = 0; j < 8; ++j) {
            const int p  = kk * 32 + q * 8 + j;
            const int p5 = p & 31;
            const int L  = (p & ~31) + ((p5 & 1) << 4) + (p5 >> 1);
            f2[j] = (short)rb16(w2[L * DIM + colG]);
            fg[j] = (short)rb16(w2g[L * DIM + colG]);
        }
        w2f[kk] = f2; w2gf[kk] = fg;
    }
    // biases: b1' = b1 + lb@w1 ; cs1 = sum_k wg_s[k][colG] ; bgv = bg + b2@wg_r
    float b1vA = b1[colA], b1vB = b1[colB], cs1 = 0.f;
    for (int k = 0; k < DIM; ++k) {
        const float lbk = ln_b[k];
        b1vA = fmaf(lbk, w1[k * HID + colA], b1vA);
        b1vB = fmaf(lbk, w1[k * HID + colB], b1vB);
        cs1 += wg[k * DIM + colG];
    }
    const float b2v = b2[colG];
    const float bgv = w2g[256 * DIM + colG];

    const int nTiles = nrows / MT;
    for (int tile = blockIdx.x; tile < nTiles; tile += gridDim.x) {
        float st[16];
        {
            const float* xr = x + (size_t)(tile * MT + hrow) * DIM + hcg;
#pragma unroll
            for (int v = 0; v < 4; ++v) {
                f32x4 a = *(const f32x4*)(xr + 4 * v);
#pragma unroll
                for (int j = 0; j < 4; ++j) st[4 * v + j] = a[j];
            }
        }

        for (int p = 0; p < np; ++p) {
            // ---- hub: state += delta (p>0), LN -> h' = (st-mu)*rs ----
            if (p > 0) {
#pragma unroll
                for (int v = 0; v < 4; ++v) {
                    f32x4 d = *(f32x4*)&dBuf[hrow * D_STRIDE + hcg + 4 * v];
#pragma unroll
                    for (int j = 0; j < 4; ++j) st[4 * v + j] += d[j];
                }
            }
            float s1 = 0.f, s2 = 0.f;
#pragma unroll
            for (int j = 0; j < 16; ++j) { s1 += st[j]; s2 = fmaf(st[j], st[j], s2); }
#pragma unroll
            for (int m = 4; m >= 1; m >>= 1) { s1 += __shfl_xor(s1, m); s2 += __shfl_xor(s2, m); }
            const float mu = s1 * (1.f / DIM);
            const float ve = fmaf(-mu, mu, s2 * (1.f / DIM)) + 1e-5f;
            const float rs = rsqrtf(ve);
            const float sg = ve * rs;
            const float mrs = mu * rs;
            unsigned int hp[8];
#pragma unroll
            for (int j = 0; j < 8; ++j)
                hp[j] = pack2(fmaf(st[2 * j], rs, -mrs), fmaf(st[2 * j + 1], rs, -mrs));
            u32x4 h0 = {hp[0], hp[1], hp[2], hp[3]}, h1 = {hp[4], hp[5], hp[6], hp[7]};
            *(u32x4*)&hBuf[hrow * H_STRIDE + hcg]     = h0;
            *(u32x4*)&hBuf[hrow * H_STRIDE + hcg + 8] = h1;
            if ((tid & 7) == 0) { muB[hrow] = mu; sgB[hrow] = sg; }
            __syncthreads();

            // ---- stage 1: [t0 t1 | gs] = h' @ [w1' | wg_s], K=128 ----
            f32x4 acc0[4], acc1[4], accg[4];
#pragma unroll
            for (int rt = 0; rt < 4; ++rt) {
                acc0[rt] = splat4(b1vA); acc1[rt] = splat4(b1vB); accg[rt] = splat4(0.f);
            }
#pragma unroll
            for (int rt = 0; rt < 4; ++rt)
#pragma unroll
                for (int kk = 0; kk < 4; ++kk) {
                    bf16x8 a = *(bf16x8*)&hBuf[(rt * 16 + c16) * H_STRIDE + kk * 32 + q * 8];
                    acc0[rt] = MFMA(a, w1f[0][kk], acc0[rt]);
                    acc1[rt] = MFMA(a, w1f[1][kk], acc1[rt]);
                    accg[rt] = MFMA(a, wgsf[kk], accg[rt]);
                }
            // epilogue: gelu -> packed gBuf; rescale gs with per-row stats
#pragma unroll
            for (int rt = 0; rt < 4; ++rt) {
                f32x4 muv = *(f32x4*)&muB[rt * 16 + q * 4];
                f32x4 sgv = *(f32x4*)&sgB[rt * 16 + q * 4];
#pragma unroll
                for (int r = 0; r < 4; ++r) {
                    const int row = rt * 16 + q * 4 + r;
                    gBuf32[row * (G_STRIDE / 2) + 16 * w + c16] =
                        pack2(gelu_f(acc0[rt][r]), gelu_f(acc1[rt][r]));
                    accg[rt][r] = fmaf(sgv[r], accg[rt][r], muv[r] * cs1);
                }
            }
            __syncthreads();

            // ---- stage 2: [refined | gr] = g @ [w2 | w2g], K=256 ----
            f32x4 acc2[4], accr[4];
#pragma unroll
            for (int rt = 0; rt < 4; ++rt) { acc2[rt] = splat4(b2v); accr[rt] = splat4(bgv); }
#pragma unroll
            for (int rt = 0; rt < 4; ++rt)
#pragma unroll
                for (int kk = 0; kk < 8; ++kk) {
                    bf16x8 a = *(bf16x8*)&gBuf[(rt * 16 + c16) * G_STRIDE + kk * 32 + q * 8];
                    acc2[rt] = MFMA(a, w2f[kk], acc2[rt]);
                    accr[rt] = MFMA(a, w2gf[kk], accr[rt]);
                }
            // all waves read all of gBuf; dBuf overlays it -> barrier before overwrite
            __syncthreads();
            // epilogue: gate = sigm(gs + gr); delta = gate * refined -> dBuf
#pragma unroll
            for (int rt = 0; rt < 4; ++rt)
#pragma unroll
                for (int r = 0; r < 4; ++r) {
                    const int row = rt * 16 + q * 4 + r;
                    const float gate = sigm(accg[rt][r] + accr[rt][r]);
                    dBuf[row * D_STRIDE + 16 * w + c16] = gate * acc2[rt][r];
                }
            __syncthreads();
        }

        // final state += delta; store
        {
            float* orow = out + (size_t)(tile * MT + hrow) * DIM + hcg;
#pragma unroll
            for (int v = 0; v < 4; ++v) {
                f32x4 d = *(f32x4*)&dBuf[hrow * D_STRIDE + hcg + 4 * v];
                f32x4 o;
#pragma unroll
                for (int j = 0; j < 4; ++j) o[j] = st[4 * v + j] + d[j];
                *(f32x4*)(orow + 4 * v) = o;
            }
        }
    }
}

extern "C" void kernel_launch(void* const* d_in, const int* in_sizes, int n_in,
                              void* d_out, int out_size, void* d_ws, size_t ws_size,
                              hipStream_t stream) {
    const float* x    = (const float*)d_in[0];
    const float* ln_w = (const float*)d_in[1];
    const float* ln_b = (const float*)d_in[2];
    const float* w1   = (const float*)d_in[3];
    const float* b1   = (const float*)d_in[4];
    const float* w2   = (const float*)d_in[5];
    const float* b2   = (const float*)d_in[6];
    const float* wg   = (const float*)d_in[7];
    const float* bg   = (const float*)d_in[8];
    const int* passes = (const int*)d_in[9];
    float* out = (float*)d_out;
    float* w2g = (float*)d_ws;  // 257*128 fp32 = 131584 B

    const int nrows = in_sizes[0] / DIM;
    hipLaunchKernelGGL(w2g_setup, dim3(8), dim3(256), 0, stream, w2, wg, b2, bg, w2g);
    hipLaunchKernelGGL(trw_kernel, dim3(1024), dim3(NT), 0, stream,
                       x, ln_w, ln_b, w1, b1, w2, b2, wg, w2g, passes, out, nrows);
}

// Round 2
// 1031.245 us; speedup vs baseline: 2.1769x; 2.1769x over previous
//
#include <hip/hip_runtime.h>
#include <math.h>

#define DIM 128
#define HID 256
#define MT 64           // rows per block-tile
#define NT 512          // threads per block (8 waves)
#define H_STRIDE 136    // bf16 elems (68 dw ≡ 4 mod 32)
#define G_STRIDE 264    // bf16 elems (132 dw ≡ 4 mod 32), k-permuted packed layout
#define D_STRIDE 132    // f32 elems (132 dw ≡ 4 mod 32; write pattern is 2-way = free)

typedef __attribute__((ext_vector_type(8))) short bf16x8;
typedef __attribute__((ext_vector_type(4))) float f32x4;
typedef __attribute__((ext_vector_type(4))) unsigned int u32x4;

#define MFMA(a, b, c) __builtin_amdgcn_mfma_f32_16x16x32_bf16((a), (b), (c), 0, 0, 0)

__device__ __forceinline__ unsigned int pack2(float lo, float hi) {
    unsigned int a = __float_as_uint(lo) + 0x8000u;
    unsigned int b = __float_as_uint(hi) + 0x8000u;
    return __builtin_amdgcn_perm(b, a, 0x07060302u);  // [b.hi16 | a.hi16]
}
__device__ __forceinline__ unsigned short rb16(float f) {
    return (unsigned short)((__float_as_uint(f) + 0x8000u) >> 16);
}
__device__ __forceinline__ float frcp(float x) { return __builtin_amdgcn_rcpf(x); }
__device__ __forceinline__ float ex2(float x)  { return __builtin_amdgcn_exp2f(x); }
// tanh-form GELU, exp folded to exp2: g = t * 1/(1+2^(t*(A + B t^2)))
__device__ __forceinline__ float gelu_f(float t) {
    const float u = t * fmaf(t * t, -0.1029436f, -2.3022082f);
    return t * frcp(1.f + ex2(u));
}
__device__ __forceinline__ float sigm(float x) { return frcp(1.f + ex2(-1.442695f * x)); }
__device__ __forceinline__ f32x4 splat4(float v) { f32x4 r = {v, v, v, v}; return r; }

// ---- setup: w2g = w2 @ wg_r (256x128 @ 128x128) -> ws fp32; row 256 = bg + b2 @ wg_r ----
__global__ void w2g_setup(const float* __restrict__ w2, const float* __restrict__ wg,
                          const float* __restrict__ b2, const float* __restrict__ bg,
                          float* __restrict__ w2g)
{
    __shared__ float wr[DIM][DIM + 1];
    const int t = threadIdx.x;  // 256
    for (int i = t; i < DIM * DIM; i += 256)
        wr[i >> 7][i & 127] = wg[DIM * DIM + i];  // wg_r = wg[128:,:]
    __syncthreads();
    const int row = blockIdx.x * 32 + (t >> 3);  // 8 blocks x 32 rows
    const int c0  = (t & 7) * 16;
    float acc[16];
#pragma unroll
    for (int j = 0; j < 16; ++j) acc[j] = 0.f;
    for (int k = 0; k < DIM; ++k) {
        const float a = w2[row * DIM + k];
#pragma unroll
        for (int j = 0; j < 16; ++j) acc[j] = fmaf(a, wr[k][c0 + j], acc[j]);
    }
#pragma unroll
    for (int j = 0; j < 16; ++j) w2g[row * DIM + c0 + j] = acc[j];
    if (blockIdx.x == 0 && t < DIM) {
        float s = bg[t];
        for (int k = 0; k < DIM; ++k) s = fmaf(b2[k], wr[k][t], s);
        w2g[256 * DIM + t] = s;
    }
}

// __launch_bounds__(NT, 2): empirically this hipcc treats the 2nd arg CUDA-style
// (min BLOCKS/CU). Arg=4 forced VGPR=64 -> massive scratch spills (FETCH 138MB->5.5GB,
// dur 852->2178us, round 1). Arg=2 -> 16 waves/CU -> VGPR cap 128 = the natural
// allocation of this kernel (round 0), zero spills, 2 blocks/CU with 51712B LDS.
__global__ __launch_bounds__(NT, 2) void trw_kernel(
    const float* __restrict__ x,
    const float* __restrict__ ln_w, const float* __restrict__ ln_b,
    const float* __restrict__ w1, const float* __restrict__ b1,
    const float* __restrict__ w2, const float* __restrict__ b2,
    const float* __restrict__ wg,
    const float* __restrict__ w2g,
    const int* __restrict__ passes_p,
    float* __restrict__ out, int nrows)
{
    // gBuf (bf16 g, stage1-epi -> stage2 reads) and dBuf (f32 delta, stage2-epi -> next hub)
    // have disjoint lifetimes (a barrier separates the last gBuf read from the first dBuf
    // write) and identical footprints (G_STRIDE/2 == D_STRIDE == 132 dw), so they overlay.
    // LDS: 17408 + 33792 + 256 + 256 = 51712 B -> 2 blocks/CU (vs 85504 B = 1 block/CU).
    __shared__ __align__(16) unsigned short hBuf[MT * H_STRIDE];  // 17408 B
    __shared__ __align__(16) unsigned int gdBuf[MT * D_STRIDE];   // 33792 B overlay
    __shared__ __align__(16) float muB[MT];
    __shared__ __align__(16) float sgB[MT];
    unsigned short* gBuf = (unsigned short*)gdBuf;
    unsigned int* gBuf32 = gdBuf;
    float* dBuf = (float*)gdBuf;

    const int tid = threadIdx.x;
    const int w = tid >> 6, l = tid & 63, q = l >> 4, c16 = l & 15;
    const int hrow = tid >> 3;          // hub: 64 rows, 8 threads/row
    const int hcg  = (tid & 7) << 4;    // hub: 16 cols/thread
    const int np = passes_p[0];

    // ---- stage-1 B-frags: w1' = lw∘w1 coltiles {2w,2w+1}; wg_s coltile {w} ----
    const int colA = 32 * w + c16, colB = colA + 16, colG = 16 * w + c16;
    bf16x8 w1f[2][4], wgsf[4];
#pragma unroll
    for (int kk = 0; kk < 4; ++kk) {
        bf16x8 fa, fb, fg;
#pragma unroll
        for (int j = 0; j < 8; ++j) {
            const int k = kk * 32 + q * 8 + j;
            const float lwk = ln_w[k];
            fa[j] = (short)rb16(lwk * w1[k * HID + colA]);
            fb[j] = (short)rb16(lwk * w1[k * HID + colB]);
            fg[j] = (short)rb16(wg[k * DIM + colG]);
        }
        w1f[0][kk] = fa; w1f[1][kk] = fb; wgsf[kk] = fg;
    }
    // ---- stage-2 B-frags (k-permuted to match gBuf packing): w2 and w2g, coltile {w} ----
    bf16x8 w2f[8], w2gf[8];
#pragma unroll
    for (int kk = 0; kk < 8; ++kk) {
        bf16x8 f2, fg;
#pragma unroll
        for (int j = 0; j < 8; ++j) {
            const int p  = kk * 32 + q * 8 + j;
            const int p5 = p & 31;
            const int L  = (p & ~31) + ((p5 & 1) << 4) + (p5 >> 1);
            f2[j] = (short)rb16(w2[L * DIM + colG]);
            fg[j] = (short)rb16(w2g[L * DIM + colG]);
        }
        w2f[kk] = f2; w2gf[kk] = fg;
    }
    // biases: b1' = b1 + lb@w1 ; cs1 = sum_k wg_s[k][colG] ; bgv = bg + b2@wg_r
    float b1vA = b1[colA], b1vB = b1[colB], cs1 = 0.f;
    for (int k = 0; k < DIM; ++k) {
        const float lbk = ln_b[k];
        b1vA = fmaf(lbk, w1[k * HID + colA], b1vA);
        b1vB = fmaf(lbk, w1[k * HID + colB], b1vB);
        cs1 += wg[k * DIM + colG];
    }
    const float b2v = b2[colG];
    const float bgv = w2g[256 * DIM + colG];

    const int nTiles = nrows / MT;
    for (int tile = blockIdx.x; tile < nTiles; tile += gridDim.x) {
        float st[16];
        {
            const float* xr = x + (size_t)(tile * MT + hrow) * DIM + hcg;
#pragma unroll
            for (int v = 0; v < 4; ++v) {
                f32x4 a = *(const f32x4*)(xr + 4 * v);
#pragma unroll
                for (int j = 0; j < 4; ++j) st[4 * v + j] = a[j];
            }
        }

        for (int p = 0; p < np; ++p) {
            // ---- hub: state += delta (p>0), LN -> h' = (st-mu)*rs ----
            if (p > 0) {
#pragma unroll
                for (int v = 0; v < 4; ++v) {
                    f32x4 d = *(f32x4*)&dBuf[hrow * D_STRIDE + hcg + 4 * v];
#pragma unroll
                    for (int j = 0; j < 4; ++j) st[4 * v + j] += d[j];
                }
            }
            float s1 = 0.f, s2 = 0.f;
#pragma unroll
            for (int j = 0; j < 16; ++j) { s1 += st[j]; s2 = fmaf(st[j], st[j], s2); }
#pragma unroll
            for (int m = 4; m >= 1; m >>= 1) { s1 += __shfl_xor(s1, m); s2 += __shfl_xor(s2, m); }
            const float mu = s1 * (1.f / DIM);
            const float ve = fmaf(-mu, mu, s2 * (1.f / DIM)) + 1e-5f;
            const float rs = rsqrtf(ve);
            const float sg = ve * rs;
            const float mrs = mu * rs;
            unsigned int hp[8];
#pragma unroll
            for (int j = 0; j < 8; ++j)
                hp[j] = pack2(fmaf(st[2 * j], rs, -mrs), fmaf(st[2 * j + 1], rs, -mrs));
            u32x4 h0 = {hp[0], hp[1], hp[2], hp[3]}, h1 = {hp[4], hp[5], hp[6], hp[7]};
            *(u32x4*)&hBuf[hrow * H_STRIDE + hcg]     = h0;
            *(u32x4*)&hBuf[hrow * H_STRIDE + hcg + 8] = h1;
            if ((tid & 7) == 0) { muB[hrow] = mu; sgB[hrow] = sg; }
            __syncthreads();

            // ---- stage 1: [t0 t1 | gs] = h' @ [w1' | wg_s], K=128 ----
            f32x4 acc0[4], acc1[4], accg[4];
#pragma unroll
            for (int rt = 0; rt < 4; ++rt) {
                acc0[rt] = splat4(b1vA); acc1[rt] = splat4(b1vB); accg[rt] = splat4(0.f);
            }
#pragma unroll
            for (int rt = 0; rt < 4; ++rt)
#pragma unroll
                for (int kk = 0; kk < 4; ++kk) {
                    bf16x8 a = *(bf16x8*)&hBuf[(rt * 16 + c16) * H_STRIDE + kk * 32 + q * 8];
                    acc0[rt] = MFMA(a, w1f[0][kk], acc0[rt]);
                    acc1[rt] = MFMA(a, w1f[1][kk], acc1[rt]);
                    accg[rt] = MFMA(a, wgsf[kk], accg[rt]);
                }
            // epilogue: gelu -> packed gBuf; rescale gs with per-row stats
#pragma unroll
            for (int rt = 0; rt < 4; ++rt) {
                f32x4 muv = *(f32x4*)&muB[rt * 16 + q * 4];
                f32x4 sgv = *(f32x4*)&sgB[rt * 16 + q * 4];
#pragma unroll
                for (int r = 0; r < 4; ++r) {
                    const int row = rt * 16 + q * 4 + r;
                    gBuf32[row * (G_STRIDE / 2) + 16 * w + c16] =
                        pack2(gelu_f(acc0[rt][r]), gelu_f(acc1[rt][r]));
                    accg[rt][r] = fmaf(sgv[r], accg[rt][r], muv[r] * cs1);
                }
            }
            __syncthreads();

            // ---- stage 2: [refined | gr] = g @ [w2 | w2g], K=256 ----
            f32x4 acc2[4], accr[4];
#pragma unroll
            for (int rt = 0; rt < 4; ++rt) { acc2[rt] = splat4(b2v); accr[rt] = splat4(bgv); }
#pragma unroll
            for (int rt = 0; rt < 4; ++rt)
#pragma unroll
                for (int kk = 0; kk < 8; ++kk) {
                    bf16x8 a = *(bf16x8*)&gBuf[(rt * 16 + c16) * G_STRIDE + kk * 32 + q * 8];
                    acc2[rt] = MFMA(a, w2f[kk], acc2[rt]);
                    accr[rt] = MFMA(a, w2gf[kk], accr[rt]);
                }
            // all waves read all of gBuf; dBuf overlays it -> barrier before overwrite
            __syncthreads();
            // epilogue: gate = sigm(gs + gr); delta = gate * refined -> dBuf
#pragma unroll
            for (int rt = 0; rt < 4; ++rt)
#pragma unroll
                for (int r = 0; r < 4; ++r) {
                    const int row = rt * 16 + q * 4 + r;
                    const float gate = sigm(accg[rt][r] + accr[rt][r]);
                    dBuf[row * D_STRIDE + 16 * w + c16] = gate * acc2[rt][r];
                }
            __syncthreads();
        }

        // final state += delta; store
        {
            float* orow = out + (size_t)(tile * MT + hrow) * DIM + hcg;
#pragma unroll
            for (int v = 0; v < 4; ++v) {
                f32x4 d = *(f32x4*)&dBuf[hrow * D_STRIDE + hcg + 4 * v];
                f32x4 o;
#pragma unroll
                for (int j = 0; j < 4; ++j) o[j] = st[4 * v + j] + d[j];
                *(f32x4*)(orow + 4 * v) = o;
            }
        }
    }
}

extern "C" void kernel_launch(void* const* d_in, const int* in_sizes, int n_in,
                              void* d_out, int out_size, void* d_ws, size_t ws_size,
                              hipStream_t stream) {
    const float* x    = (const float*)d_in[0];
    const float* ln_w = (const float*)d_in[1];
    const float* ln_b = (const float*)d_in[2];
    const float* w1   = (const float*)d_in[3];
    const float* b1   = (const float*)d_in[4];
    const float* w2   = (const float*)d_in[5];
    const float* b2   = (const float*)d_in[6];
    const float* wg   = (const float*)d_in[7];
    const float* bg   = (const float*)d_in[8];
    const int* passes = (const int*)d_in[9];
    float* out = (float*)d_out;
    float* w2g = (float*)d_ws;  // 257*128 fp32 = 131584 B

    const int nrows = in_sizes[0] / DIM;
    hipLaunchKernelGGL(w2g_setup, dim3(8), dim3(256), 0, stream, w2, wg, b2, bg, w2g);
    hipLaunchKernelGGL(trw_kernel, dim3(1024), dim3(NT), 0, stream,
                       x, ln_w, ln_b, w1, b1, w2, b2, wg, w2g, passes, out, nrows);
}

// Round 3
// 964.836 us; speedup vs baseline: 2.3267x; 1.0688x over previous
//
#include <hip/hip_runtime.h>
#include <math.h>

#define DIM 128
#define HID 256
#define MT 64           // rows per block-tile (2 sub-tiles of 32)
#define NT 512          // threads per block (8 waves)
#define H_STRIDE 136    // bf16 elems (68 dw ≡ 4 mod 32)
#define G_STRIDE 264    // bf16 elems (132 dw ≡ 4 mod 32), k-permuted packed layout
#define D_STRIDE 132    // f32 elems

typedef __attribute__((ext_vector_type(8))) short bf16x8;
typedef __attribute__((ext_vector_type(4))) float f32x4;
typedef __attribute__((ext_vector_type(4))) unsigned int u32x4;

#define MFMA(a, b, c) __builtin_amdgcn_mfma_f32_16x16x32_bf16((a), (b), (c), 0, 0, 0)

__device__ __forceinline__ unsigned int pack2(float lo, float hi) {
    unsigned int a = __float_as_uint(lo) + 0x8000u;
    unsigned int b = __float_as_uint(hi) + 0x8000u;
    return __builtin_amdgcn_perm(b, a, 0x07060302u);  // [b.hi16 | a.hi16]
}
__device__ __forceinline__ unsigned short rb16(float f) {
    return (unsigned short)((__float_as_uint(f) + 0x8000u) >> 16);
}
__device__ __forceinline__ float frcp(float x) { return __builtin_amdgcn_rcpf(x); }
__device__ __forceinline__ float ex2(float x)  { return __builtin_amdgcn_exp2f(x); }
__device__ __forceinline__ float gelu_f(float t) {
    const float u = t * fmaf(t * t, -0.1029436f, -2.3022082f);
    return t * frcp(1.f + ex2(u));
}
__device__ __forceinline__ float sigm(float x) { return frcp(1.f + ex2(-1.442695f * x)); }
__device__ __forceinline__ f32x4 splat4(float v) { f32x4 r = {v, v, v, v}; return r; }

// ---- setup: w2g = w2 @ wg_r (256x128 @ 128x128) -> ws fp32; row 256 = bg + b2 @ wg_r ----
__global__ void w2g_setup(const float* __restrict__ w2, const float* __restrict__ wg,
                          const float* __restrict__ b2, const float* __restrict__ bg,
                          float* __restrict__ w2g)
{
    __shared__ float wr[DIM][DIM + 1];
    const int t = threadIdx.x;  // 256
    for (int i = t; i < DIM * DIM; i += 256)
        wr[i >> 7][i & 127] = wg[DIM * DIM + i];  // wg_r = wg[128:,:]
    __syncthreads();
    const int row = blockIdx.x * 32 + (t >> 3);  // 8 blocks x 32 rows
    const int c0  = (t & 7) * 16;
    float acc[16];
#pragma unroll
    for (int j = 0; j < 16; ++j) acc[j] = 0.f;
    for (int k = 0; k < DIM; ++k) {
        const float a = w2[row * DIM + k];
#pragma unroll
        for (int j = 0; j < 16; ++j) acc[j] = fmaf(a, wr[k][c0 + j], acc[j]);
    }
#pragma unroll
    for (int j = 0; j < 16; ++j) w2g[row * DIM + c0 + j] = acc[j];
    if (blockIdx.x == 0 && t < DIM) {
        float s = bg[t];
        for (int k = 0; k < DIM; ++k) s = fmaf(b2[k], wr[k][t], s);
        w2g[256 * DIM + t] = s;
    }
}

// Occupancy analysis: weights (112 VGPR) + state + accs ~= 200-256 arch+acc regs/wave
// -> 8 waves/CU hard (register-limited, 1 block/CU). So instead of chasing occupancy,
// overlap MFMA and VALU pipes *within* the block: two 32-row sub-tiles pipelined one
// phase apart, so every barrier region holds one sub-tile's MFMA and the other's
// VALU-heavy hub/epilogue. 3 barriers/pass (overlay reverted; LDS irrelevant at 1 blk).
__global__ __launch_bounds__(NT) void trw_kernel(
    const float* __restrict__ x,
    const float* __restrict__ ln_w, const float* __restrict__ ln_b,
    const float* __restrict__ w1, const float* __restrict__ b1,
    const float* __restrict__ w2, const float* __restrict__ b2,
    const float* __restrict__ wg,
    const float* __restrict__ w2g,
    const int* __restrict__ passes_p,
    float* __restrict__ out, int nrows)
{
    __shared__ __align__(16) unsigned short hBuf[MT * H_STRIDE];  // 17408 B
    __shared__ __align__(16) unsigned short gBuf[MT * G_STRIDE];  // 33792 B
    __shared__ __align__(16) float dBuf[MT * D_STRIDE];           // 33792 B
    __shared__ __align__(16) float muB[MT];
    __shared__ __align__(16) float sgB[MT];
    unsigned int* gBuf32 = (unsigned int*)gBuf;

    const int tid = threadIdx.x;
    const int w = tid >> 6, l = tid & 63, q = l >> 4, c16 = l & 15;
    const int r16 = tid >> 4;           // hub: 32 rows/sub-tile, 16 threads/row
    const int hc  = (tid & 15) << 3;    // hub: 8 cols/thread
    const int np = passes_p[0];

    // ---- stage-1 B-frags: w1' = lw∘w1 coltiles {2w,2w+1}; wg_s coltile {w} ----
    const int colA = 32 * w + c16, colB = colA + 16, colG = 16 * w + c16;
    bf16x8 w1f[2][4], wgsf[4];
#pragma unroll
    for (int kk = 0; kk < 4; ++kk) {
        bf16x8 fa, fb, fg;
#pragma unroll
        for (int j = 0; j < 8; ++j) {
            const int k = kk * 32 + q * 8 + j;
            const float lwk = ln_w[k];
            fa[j] = (short)rb16(lwk * w1[k * HID + colA]);
            fb[j] = (short)rb16(lwk * w1[k * HID + colB]);
            fg[j] = (short)rb16(wg[k * DIM + colG]);
        }
        w1f[0][kk] = fa; w1f[1][kk] = fb; wgsf[kk] = fg;
    }
    // ---- stage-2 B-frags (k-permuted to match gBuf packing): w2 and w2g, coltile {w} ----
    bf16x8 w2f[8], w2gf[8];
#pragma unroll
    for (int kk = 0; kk < 8; ++kk) {
        bf16x8 f2, fg;
#pragma unroll
        for (int j = 0; j < 8; ++j) {
            const int p  = kk * 32 + q * 8 + j;
            const int p5 = p & 31;
            const int L  = (p & ~31) + ((p5 & 1) << 4) + (p5 >> 1);
            f2[j] = (short)rb16(w2[L * DIM + colG]);
            fg[j] = (short)rb16(w2g[L * DIM + colG]);
        }
        w2f[kk] = f2; w2gf[kk] = fg;
    }
    // biases: b1' = b1 + lb@w1 ; cs1 = sum_k wg_s[k][colG] ; bgv = bg + b2@wg_r
    float b1vA = b1[colA], b1vB = b1[colB], cs1 = 0.f;
    for (int k = 0; k < DIM; ++k) {
        const float lbk = ln_b[k];
        b1vA = fmaf(lbk, w1[k * HID + colA], b1vA);
        b1vB = fmaf(lbk, w1[k * HID + colB], b1vB);
        cs1 += wg[k * DIM + colG];
    }
    const float b2v = b2[colG];
    const float bgv = w2g[256 * DIM + colG];

    // ---- per-phase bodies (S = sub-tile literal 0/1) ----
    // HUB: st += dBuf (if ADD), LN stats over 16-lane row group, pack h' -> hBuf
#define HUB(S, ADD)                                                                     \
    {                                                                                   \
        if (ADD) {                                                                      \
            _Pragma("unroll")                                                           \
            for (int v = 0; v < 2; ++v) {                                               \
                f32x4 d = *(f32x4*)&dBuf[((S)*32 + r16) * D_STRIDE + hc + 4 * v];       \
                _Pragma("unroll")                                                       \
                for (int j = 0; j < 4; ++j) st##S[4 * v + j] += d[j];                   \
            }                                                                           \
        }                                                                               \
        float s1 = 0.f, s2 = 0.f;                                                       \
        _Pragma("unroll")                                                               \
        for (int j = 0; j < 8; ++j) { s1 += st##S[j]; s2 = fmaf(st##S[j], st##S[j], s2); } \
        _Pragma("unroll")                                                               \
        for (int m = 8; m >= 1; m >>= 1) { s1 += __shfl_xor(s1, m); s2 += __shfl_xor(s2, m); } \
        const float mu = s1 * (1.f / DIM);                                              \
        const float ve = fmaf(-mu, mu, s2 * (1.f / DIM)) + 1e-5f;                       \
        const float rs = rsqrtf(ve);                                                    \
        const float sg = ve * rs;                                                       \
        const float mrs = mu * rs;                                                      \
        unsigned int hp[4];                                                             \
        _Pragma("unroll")                                                               \
        for (int j = 0; j < 4; ++j)                                                     \
            hp[j] = pack2(fmaf(st##S[2 * j], rs, -mrs), fmaf(st##S[2 * j + 1], rs, -mrs)); \
        u32x4 hv = {hp[0], hp[1], hp[2], hp[3]};                                        \
        *(u32x4*)&hBuf[((S)*32 + r16) * H_STRIDE + hc] = hv;                            \
        if ((tid & 15) == 0) { muB[(S)*32 + r16] = mu; sgB[(S)*32 + r16] = sg; }        \
    }

    // M1E1: stage-1 MFMA (K=128) + gelu epilogue -> gBuf; gs kept in regs for E2
#define M1E1(S, GS)                                                                     \
    {                                                                                   \
        f32x4 acc0[2], acc1[2], accg[2];                                                \
        _Pragma("unroll")                                                               \
        for (int rt = 0; rt < 2; ++rt) {                                                \
            acc0[rt] = splat4(b1vA); acc1[rt] = splat4(b1vB); accg[rt] = splat4(0.f);   \
        }                                                                               \
        _Pragma("unroll")                                                               \
        for (int rt = 0; rt < 2; ++rt)                                                  \
            _Pragma("unroll")                                                           \
            for (int kk = 0; kk < 4; ++kk) {                                            \
                bf16x8 a = *(bf16x8*)&hBuf[((S)*32 + rt * 16 + c16) * H_STRIDE + kk * 32 + q * 8]; \
                acc0[rt] = MFMA(a, w1f[0][kk], acc0[rt]);                               \
                acc1[rt] = MFMA(a, w1f[1][kk], acc1[rt]);                               \
                accg[rt] = MFMA(a, wgsf[kk], accg[rt]);                                 \
            }                                                                           \
        _Pragma("unroll")                                                               \
        for (int rt = 0; rt < 2; ++rt) {                                                \
            f32x4 muv = *(f32x4*)&muB[(S)*32 + rt * 16 + q * 4];                        \
            f32x4 sgv = *(f32x4*)&sgB[(S)*32 + rt * 16 + q * 4];                        \
            _Pragma("unroll")                                                           \
            for (int r = 0; r < 4; ++r) {                                               \
                const int row = (S)*32 + rt * 16 + q * 4 + r;                           \
                gBuf32[row * (G_STRIDE / 2) + 16 * w + c16] =                           \
                    pack2(gelu_f(acc0[rt][r]), gelu_f(acc1[rt][r]));                    \
                GS[rt][r] = fmaf(sgv[r], accg[rt][r], muv[r] * cs1);                    \
            }                                                                           \
        }                                                                               \
    }

    // M2E2: stage-2 MFMA (K=256) + gate epilogue -> dBuf
#define M2E2(S, GS)                                                                     \
    {                                                                                   \
        f32x4 acc2[2], accr[2];                                                         \
        _Pragma("unroll")                                                               \
        for (int rt = 0; rt < 2; ++rt) { acc2[rt] = splat4(b2v); accr[rt] = splat4(bgv); } \
        _Pragma("unroll")                                                               \
        for (int rt = 0; rt < 2; ++rt)                                                  \
            _Pragma("unroll")                                                           \
            for (int kk = 0; kk < 8; ++kk) {                                            \
                bf16x8 a = *(bf16x8*)&gBuf[((S)*32 + rt * 16 + c16) * G_STRIDE + kk * 32 + q * 8]; \
                acc2[rt] = MFMA(a, w2f[kk], acc2[rt]);                                  \
                accr[rt] = MFMA(a, w2gf[kk], accr[rt]);                                 \
            }                                                                           \
        _Pragma("unroll")                                                               \
        for (int rt = 0; rt < 2; ++rt)                                                  \
            _Pragma("unroll")                                                           \
            for (int r = 0; r < 4; ++r) {                                               \
                const int row = (S)*32 + rt * 16 + q * 4 + r;                           \
                const float gate = sigm(GS[rt][r] + accr[rt][r]);                       \
                dBuf[row * D_STRIDE + 16 * w + c16] = gate * acc2[rt][r];               \
            }                                                                           \
    }

    // FIN: st += dBuf, store to out
#define FIN(S)                                                                          \
    {                                                                                   \
        float* orow = out + (size_t)(tile * MT + (S)*32 + r16) * DIM + hc;              \
        _Pragma("unroll")                                                               \
        for (int v = 0; v < 2; ++v) {                                                   \
            f32x4 d = *(f32x4*)&dBuf[((S)*32 + r16) * D_STRIDE + hc + 4 * v];           \
            f32x4 o;                                                                    \
            _Pragma("unroll")                                                           \
            for (int j = 0; j < 4; ++j) o[j] = st##S[4 * v + j] + d[j];                 \
            *(f32x4*)(orow + 4 * v) = o;                                                \
        }                                                                               \
    }

    const int nTiles = nrows / MT;
    for (int tile = blockIdx.x; tile < nTiles; tile += gridDim.x) {
        float st0[8], st1[8];
        {
            const float* xr0 = x + (size_t)(tile * MT + r16) * DIM + hc;
            const float* xr1 = xr0 + 32 * DIM;
#pragma unroll
            for (int v = 0; v < 2; ++v) {
                f32x4 a0 = *(const f32x4*)(xr0 + 4 * v);
                f32x4 a1 = *(const f32x4*)(xr1 + 4 * v);
#pragma unroll
                for (int j = 0; j < 4; ++j) { st0[4 * v + j] = a0[j]; st1[4 * v + j] = a1[j]; }
            }
        }

        f32x4 gsA[2], gsB[2];

        // prologue: sub-tile 1 runs one phase ahead
        HUB(1, false)
        __syncthreads();

        for (int p = 0; p < np; ++p) {
            // phase X: stage-1(B) MFMA+gelu  ||  hub(A) VALU
            M1E1(1, gsB)
            HUB(0, (p > 0))
            __syncthreads();
            // phase Y: stage-2(B) MFMA+gate  ||  stage-1(A) MFMA+gelu
            M2E2(1, gsB)
            M1E1(0, gsA)
            __syncthreads();
            // phase Z: hub(B,next)/finalize(B) VALU  ||  stage-2(A) MFMA+gate
            if (p < np - 1) {
                HUB(1, true)
            } else {
                FIN(1)
            }
            M2E2(0, gsA)
            __syncthreads();
        }
        FIN(0)
        // next tile's prologue HUB(1) touches hBuf/muB rows 32-63 only; FIN reads
        // dBuf rows 0-31 — disjoint, and the prologue barrier orders the rest.
    }
#undef HUB
#undef M1E1
#undef M2E2
#undef FIN
}

extern "C" void kernel_launch(void* const* d_in, const int* in_sizes, int n_in,
                              void* d_out, int out_size, void* d_ws, size_t ws_size,
                              hipStream_t stream) {
    const float* x    = (const float*)d_in[0];
    const float* ln_w = (const float*)d_in[1];
    const float* ln_b = (const float*)d_in[2];
    const float* w1   = (const float*)d_in[3];
    const float* b1   = (const float*)d_in[4];
    const float* w2   = (const float*)d_in[5];
    const float* b2   = (const float*)d_in[6];
    const float* wg   = (const float*)d_in[7];
    const float* bg   = (const float*)d_in[8];
    const int* passes = (const int*)d_in[9];
    float* out = (float*)d_out;
    float* w2g = (float*)d_ws;  // 257*128 fp32 = 131584 B

    const int nrows = in_sizes[0] / DIM;
    hipLaunchKernelGGL(w2g_setup, dim3(8), dim3(256), 0, stream, w2, wg, b2, bg, w2g);
    hipLaunchKernelGGL(trw_kernel, dim3(1024), dim3(NT), 0, stream,
                       x, ln_w, ln_b, w1, b1, w2, b2, wg, w2g, passes, out, nrows);
}

// Round 6
// 934.866 us; speedup vs baseline: 2.4013x; 1.0321x over previous
//
#include <hip/hip_runtime.h>
#include <math.h>

#define DIM 128
#define HID 256
#define MT 64           // rows per block-tile (2 halves of 32)
#define NT 1024         // 16 waves: crew A (stage-1) = waves 0-7, crew B (stage-2) = waves 8-15
#define H_STRIDE 136    // bf16 elems
#define G_STRIDE 264    // bf16 elems, k-permuted packed layout
#define S_STRIDE 132    // f32 elems (stBuf / gsBuf)

typedef __attribute__((ext_vector_type(8))) short bf16x8;
typedef __attribute__((ext_vector_type(4))) float f32x4;
typedef __attribute__((ext_vector_type(4))) unsigned int u32x4;

#define MFMA(a, b, c) __builtin_amdgcn_mfma_f32_16x16x32_bf16((a), (b), (c), 0, 0, 0)

__device__ __forceinline__ unsigned int pack2(float lo, float hi) {
    unsigned int a = __float_as_uint(lo) + 0x8000u;
    unsigned int b = __float_as_uint(hi) + 0x8000u;
    return __builtin_amdgcn_perm(b, a, 0x07060302u);  // [b.hi16 | a.hi16]
}
__device__ __forceinline__ unsigned short rb16(float f) {
    return (unsigned short)((__float_as_uint(f) + 0x8000u) >> 16);
}
__device__ __forceinline__ float frcp(float x) { return __builtin_amdgcn_rcpf(x); }
__device__ __forceinline__ float ex2(float x)  { return __builtin_amdgcn_exp2f(x); }
__device__ __forceinline__ float gelu_f(float t) {
    const float u = t * fmaf(t * t, -0.1029436f, -2.3022082f);
    return t * frcp(1.f + ex2(u));
}
__device__ __forceinline__ float sigm(float x) { return frcp(1.f + ex2(-1.442695f * x)); }
__device__ __forceinline__ f32x4 splat4(float v) { f32x4 r = {v, v, v, v}; return r; }

// ---- setup: w2g = w2 @ wg_r (256x128 @ 128x128) -> ws fp32; row 256 = bg + b2 @ wg_r ----
__global__ void w2g_setup(const float* __restrict__ w2, const float* __restrict__ wg,
                          const float* __restrict__ b2, const float* __restrict__ bg,
                          float* __restrict__ w2g)
{
    __shared__ float wr[DIM][DIM + 1];
    const int t = threadIdx.x;  // 256
    for (int i = t; i < DIM * DIM; i += 256)
        wr[i >> 7][i & 127] = wg[DIM * DIM + i];  // wg_r = wg[128:,:]
    __syncthreads();
    const int row = blockIdx.x * 32 + (t >> 3);  // 8 blocks x 32 rows
    const int c0  = (t & 7) * 16;
    float acc[16];
#pragma unroll
    for (int j = 0; j < 16; ++j) acc[j] = 0.f;
    for (int k = 0; k < DIM; ++k) {
        const float a = w2[row * DIM + k];
#pragma unroll
        for (int j = 0; j < 16; ++j) acc[j] = fmaf(a, wr[k][c0 + j], acc[j]);
    }
#pragma unroll
    for (int j = 0; j < 16; ++j) w2g[row * DIM + c0 + j] = acc[j];
    if (blockIdx.x == 0 && t < DIM) {
        float s = bg[t];
        for (int k = 0; k < DIM; ++k) s = fmaf(b2[k], wr[k][t], s);
        w2g[256 * DIM + t] = s;
    }
}

// Wave-specialized with UNIFORM barriers: the phase loop + every __syncthreads() is
// in uniform control flow; only compute bodies are inside wave-aligned if(crewA)
// branches (legal, zero-risk). Both crews share ONE weight-fragment array wf[16]
// (64 VGPRs): crew A uses wf[0..11] = {w1'A, w1'B, wg_s}, crew B wf[0..15] =
// {w2, w2g} — so the joint allocation is max(crew needs), not sum. State lives in
// stBuf (LDS); stage-2 epilogue accumulates delta into stBuf; gs passes via gsBuf.
__global__ __launch_bounds__(NT) void trw_kernel(
    const float* __restrict__ x,
    const float* __restrict__ ln_w, const float* __restrict__ ln_b,
    const float* __restrict__ w1, const float* __restrict__ b1,
    const float* __restrict__ w2, const float* __restrict__ b2,
    const float* __restrict__ wg,
    const float* __restrict__ w2g,
    const int* __restrict__ passes_p,
    float* __restrict__ out, int nrows)
{
    __shared__ __align__(16) unsigned short hBuf[MT * H_STRIDE];  // 17408 B
    __shared__ __align__(16) unsigned short gBuf[MT * G_STRIDE];  // 33792 B
    __shared__ __align__(16) float gsBuf[MT * S_STRIDE];          // 33792 B
    __shared__ __align__(16) float stBuf[MT * S_STRIDE];          // 33792 B
    __shared__ __align__(16) float muB[MT];
    __shared__ __align__(16) float sgB[MT];
    unsigned int* gBuf32 = (unsigned int*)gBuf;

    const int tid = threadIdx.x;
    const bool crewA = (tid < 512);
    const int ct = tid & 511;           // crew-local thread id
    const int wv = (tid >> 6) & 7;      // crew-local wave id
    const int l = tid & 63, q = l >> 4, c16 = l & 15;
    const int colG = 16 * wv + c16;
    const int np = passes_p[0];
    const int nTiles = nrows / MT;

    // ---- shared weight-fragment pool + biases ----
    bf16x8 wf[16];
    {
        bf16x8 z;
#pragma unroll
        for (int j = 0; j < 8; ++j) z[j] = 0;
#pragma unroll
        for (int i = 0; i < 16; ++i) wf[i] = z;
    }
    float bias0 = 0.f, bias1 = 0.f, bias2 = 0.f;

    if (crewA) {
        // crew A: wf[kk]=w1'A, wf[4+kk]=w1'B, wf[8+kk]=wg_s ; bias0/1=b1', bias2=cs1
        const int colA = 32 * wv + c16, colB = colA + 16;
#pragma unroll
        for (int kk = 0; kk < 4; ++kk) {
#pragma unroll
            for (int j = 0; j < 8; ++j) {
                const int k = kk * 32 + q * 8 + j;
                const float lwk = ln_w[k];
                wf[kk][j]     = (short)rb16(lwk * w1[k * HID + colA]);
                wf[4 + kk][j] = (short)rb16(lwk * w1[k * HID + colB]);
                wf[8 + kk][j] = (short)rb16(wg[k * DIM + colG]);
            }
        }
        bias0 = b1[colA]; bias1 = b1[colB]; bias2 = 0.f;
        for (int k = 0; k < DIM; ++k) {
            const float lbk = ln_b[k];
            bias0 = fmaf(lbk, w1[k * HID + colA], bias0);
            bias1 = fmaf(lbk, w1[k * HID + colB], bias1);
            bias2 += wg[k * DIM + colG];
        }
    } else {
        // crew B: wf[kk]=w2 (k-permuted), wf[8+kk]=w2g ; bias0=b2, bias1=bg'
#pragma unroll
        for (int kk = 0; kk < 8; ++kk) {
#pragma unroll
            for (int j = 0; j < 8; ++j) {
                const int pk = kk * 32 + q * 8 + j;
                const int p5 = pk & 31;
                const int L  = (pk & ~31) + ((p5 & 1) << 4) + (p5 >> 1);
                wf[kk][j]     = (short)rb16(w2[L * DIM + colG]);
                wf[8 + kk][j] = (short)rb16(w2g[L * DIM + colG]);
            }
        }
        bias0 = b2[colG]; bias1 = w2g[256 * DIM + colG];
    }

#define LOADX(H)                                                                        \
    {                                                                                   \
        const int row = (H) * 32 + (ct >> 4);                                           \
        const int hc  = (ct & 15) << 3;                                                 \
        const float* xr = x + (size_t)(tile * MT + row) * DIM + hc;                     \
        *(f32x4*)&stBuf[row * S_STRIDE + hc]     = *(const f32x4*)(xr);                 \
        *(f32x4*)&stBuf[row * S_STRIDE + hc + 4] = *(const f32x4*)(xr + 4);             \
    }

#define FIN(H)                                                                          \
    {                                                                                   \
        const int row = (H) * 32 + (ct >> 4);                                           \
        const int hc  = (ct & 15) << 3;                                                 \
        float* orow = out + (size_t)(tile * MT + row) * DIM + hc;                       \
        *(f32x4*)(orow)     = *(f32x4*)&stBuf[row * S_STRIDE + hc];                     \
        *(f32x4*)(orow + 4) = *(f32x4*)&stBuf[row * S_STRIDE + hc + 4];                 \
    }

    // HUB(H): LN over stBuf rows of half H -> packed h' in hBuf + muB/sgB
#define HUB(H)                                                                          \
    {                                                                                   \
        const int row = (H) * 32 + (ct >> 4);                                           \
        const int hc  = (ct & 15) << 3;                                                 \
        f32x4 a0 = *(f32x4*)&stBuf[row * S_STRIDE + hc];                                \
        f32x4 a1 = *(f32x4*)&stBuf[row * S_STRIDE + hc + 4];                            \
        float s1 = 0.f, s2 = 0.f;                                                       \
        _Pragma("unroll")                                                               \
        for (int j = 0; j < 4; ++j) {                                                   \
            s1 += a0[j] + a1[j];                                                        \
            s2 = fmaf(a0[j], a0[j], fmaf(a1[j], a1[j], s2));                            \
        }                                                                               \
        _Pragma("unroll")                                                               \
        for (int m = 8; m >= 1; m >>= 1) { s1 += __shfl_xor(s1, m); s2 += __shfl_xor(s2, m); } \
        const float mu = s1 * (1.f / DIM);                                              \
        const float ve = fmaf(-mu, mu, s2 * (1.f / DIM)) + 1e-5f;                       \
        const float rs = rsqrtf(ve);                                                    \
        const float mrs = mu * rs;                                                      \
        u32x4 hv = {pack2(fmaf(a0[0], rs, -mrs), fmaf(a0[1], rs, -mrs)),                \
                    pack2(fmaf(a0[2], rs, -mrs), fmaf(a0[3], rs, -mrs)),                \
                    pack2(fmaf(a1[0], rs, -mrs), fmaf(a1[1], rs, -mrs)),                \
                    pack2(fmaf(a1[2], rs, -mrs), fmaf(a1[3], rs, -mrs))};               \
        *(u32x4*)&hBuf[row * H_STRIDE + hc] = hv;                                       \
        if ((ct & 15) == 0) { muB[row] = mu; sgB[row] = ve * rs; }                      \
    }

    // M1(H): crew A — [t0 t1 | gs] = h' @ [w1' | wg_s]; gelu->gBuf, gs->gsBuf
#define M1(H)                                                                           \
    {                                                                                   \
        f32x4 acc0[2], acc1[2], accg[2];                                                \
        _Pragma("unroll")                                                               \
        for (int rt = 0; rt < 2; ++rt) {                                                \
            acc0[rt] = splat4(bias0); acc1[rt] = splat4(bias1); accg[rt] = splat4(0.f); \
        }                                                                               \
        _Pragma("unroll")                                                               \
        for (int rt = 0; rt < 2; ++rt)                                                  \
            _Pragma("unroll")                                                           \
            for (int kk = 0; kk < 4; ++kk) {                                            \
                bf16x8 a = *(bf16x8*)&hBuf[((H) * 32 + rt * 16 + c16) * H_STRIDE + kk * 32 + q * 8]; \
                acc0[rt] = MFMA(a, wf[kk], acc0[rt]);                                   \
                acc1[rt] = MFMA(a, wf[4 + kk], acc1[rt]);                               \
                accg[rt] = MFMA(a, wf[8 + kk], accg[rt]);                               \
            }                                                                           \
        _Pragma("unroll")                                                               \
        for (int rt = 0; rt < 2; ++rt) {                                                \
            f32x4 muv = *(f32x4*)&muB[(H) * 32 + rt * 16 + q * 4];                      \
            f32x4 sgv = *(f32x4*)&sgB[(H) * 32 + rt * 16 + q * 4];                      \
            _Pragma("unroll")                                                           \
            for (int r = 0; r < 4; ++r) {                                               \
                const int row = (H) * 32 + rt * 16 + q * 4 + r;                         \
                gBuf32[row * (G_STRIDE / 2) + colG] =                                   \
                    pack2(gelu_f(acc0[rt][r]), gelu_f(acc1[rt][r]));                    \
                gsBuf[row * S_STRIDE + colG] = fmaf(sgv[r], accg[rt][r], muv[r] * bias2); \
            }                                                                           \
        }                                                                               \
    }

    // M2(H): crew B — [refined | gr] = g @ [w2 | w2g]; gate; delta accumulated into stBuf
#define M2(H)                                                                           \
    {                                                                                   \
        f32x4 acc2[2], accr[2];                                                         \
        _Pragma("unroll")                                                               \
        for (int rt = 0; rt < 2; ++rt) { acc2[rt] = splat4(bias0); accr[rt] = splat4(bias1); } \
        _Pragma("unroll")                                                               \
        for (int rt = 0; rt < 2; ++rt)                                                  \
            _Pragma("unroll")                                                           \
            for (int kk = 0; kk < 8; ++kk) {                                            \
                bf16x8 a = *(bf16x8*)&gBuf[((H) * 32 + rt * 16 + c16) * G_STRIDE + kk * 32 + q * 8]; \
                acc2[rt] = MFMA(a, wf[kk], acc2[rt]);                                   \
                accr[rt] = MFMA(a, wf[8 + kk], accr[rt]);                               \
            }                                                                           \
        _Pragma("unroll")                                                               \
        for (int rt = 0; rt < 2; ++rt)                                                  \
            _Pragma("unroll")                                                           \
            for (int r = 0; r < 4; ++r) {                                               \
                const int row = (H) * 32 + rt * 16 + q * 4 + r;                         \
                const int idx = row * S_STRIDE + colG;                                  \
                const float gate = sigm(gsBuf[idx] + accr[rt][r]);                      \
                stBuf[idx] += gate * acc2[rt][r];                                       \
            }                                                                           \
    }

    for (int tile = blockIdx.x; tile < nTiles; tile += gridDim.x) {
        if (crewA) { LOADX(0) } else { LOADX(1) }
        __syncthreads();                          // S1: stBuf ready
        if (!crewA) { HUB(1) }
        __syncthreads();                          // S2: hBuf(H1) ready
        for (int p = 0; p < np; ++p) {
            if (crewA) { M1(1) } else { HUB(0) }  // Phi1
            __syncthreads();                      // S3
            if (crewA) { M1(0) } else { M2(1) }   // Phi2
            __syncthreads();                      // S4
            if (crewA) { if (p < np - 1) HUB(1) } else { M2(0) }  // Phi3
            __syncthreads();                      // S5
        }
        if (crewA) { FIN(0) } else { FIN(1) }
        __syncthreads();                          // S6: protect stBuf before next LOADX
    }
#undef LOADX
#undef FIN
#undef HUB
#undef M1
#undef M2
}

extern "C" void kernel_launch(void* const* d_in, const int* in_sizes, int n_in,
                              void* d_out, int out_size, void* d_ws, size_t ws_size,
                              hipStream_t stream) {
    const float* x    = (const float*)d_in[0];
    const float* ln_w = (const float*)d_in[1];
    const float* ln_b = (const float*)d_in[2];
    const float* w1   = (const float*)d_in[3];
    const float* b1   = (const float*)d_in[4];
    const float* w2   = (const float*)d_in[5];
    const float* b2   = (const float*)d_in[6];
    const float* wg   = (const float*)d_in[7];
    const float* bg   = (const float*)d_in[8];
    const int* passes = (const int*)d_in[9];
    float* out = (float*)d_out;
    float* w2g = (float*)d_ws;  // 257*128 fp32 = 131584 B

    const int nrows = in_sizes[0] / DIM;
    hipLaunchKernelGGL(w2g_setup, dim3(8), dim3(256), 0, stream, w2, wg, b2, bg, w2g);
    hipLaunchKernelGGL(trw_kernel, dim3(1024), dim3(NT), 0, stream,
                       x, ln_w, ln_b, w1, b1, w2, b2, wg, w2g, passes, out, nrows);
}